// Round 3
// baseline (1084.187 us; speedup 1.0000x reference)
//
#include <hip/hip_runtime.h>
#include <stdint.h>

typedef unsigned short ushort_t;
typedef __attribute__((ext_vector_type(8))) short short8;
typedef __attribute__((ext_vector_type(8))) unsigned short u16x8;
typedef __attribute__((ext_vector_type(4))) float f32x4;

#define GLOBAL_AS __attribute__((address_space(1)))
#define LDS_AS __attribute__((address_space(3)))

__device__ __forceinline__ ushort_t f2bf(float f) {
  union { float f; uint32_t u; } v; v.f = f;
  uint32_t u = v.u;
  u += 0x7FFFu + ((u >> 16) & 1u);   // round-to-nearest-even
  return (ushort_t)(u >> 16);
}

// ---------------- weight transpose + bf16 cast: dst[n][k] = bf16(src[k][n]); fout = 512 always
struct TransArgs {
  const float* src[8];
  ushort_t* dst[8];
  int K[8];
  int blk0[9];
};

__global__ __launch_bounds__(256) void transpose_weights(TransArgs ta) {
  __shared__ float tile[64 * 65];
  int b = blockIdx.x;
  int mi = 0;
#pragma unroll
  for (int i = 1; i < 8; ++i) if (b >= ta.blk0[i]) mi = i;
  const float* src = ta.src[mi];
  ushort_t* dst = ta.dst[mi];
  int K = ta.K[mi];
  int rel = b - ta.blk0[mi];
  int ktiles = K >> 6;
  int k0 = (rel % ktiles) << 6;
  int n0 = (rel / ktiles) << 6;
  int t = threadIdx.x;
#pragma unroll
  for (int i = 0; i < 16; ++i) {
    int idx = i * 256 + t;
    int r = idx >> 6, c = idx & 63;
    tile[r * 65 + c] = src[(size_t)(k0 + r) * 512 + (n0 + c)];
  }
  __syncthreads();
#pragma unroll
  for (int i = 0; i < 16; ++i) {
    int idx = i * 256 + t;
    int r = idx >> 6, c = idx & 63;          // r: n-row, c: k-col
    dst[(size_t)(n0 + r) * K + (k0 + c)] = f2bf(tile[c * 65 + r]);
  }
}

// ---------------- prep: X[e][0:512]=bf16(pred), pos[e][0:128]=pos FCN (f32 math, shfl-based)
__global__ __launch_bounds__(256) void prep_kernel(
    const float* __restrict__ pred, const float* __restrict__ centroid,
    const float* __restrict__ pw1, const float* __restrict__ pb1,
    const float* __restrict__ pw2, const float* __restrict__ pb2,
    const float* __restrict__ pw3, const float* __restrict__ pb3,
    ushort_t* __restrict__ X, ushort_t* __restrict__ pos, int nm1)
{
  __shared__ float w1[5 * 64];
  __shared__ float w2[64 * 64];
  __shared__ float w3[64 * 128];
  __shared__ float b1s[64], b2s[64], b3s[128];
  int t = threadIdx.x;
  for (int i = t; i < 5 * 64; i += 256) w1[i] = pw1[i];
  for (int i = t; i < 64 * 64; i += 256) w2[i] = pw2[i];
  for (int i = t; i < 64 * 128; i += 256) w3[i] = pw3[i];
  if (t < 64) { b1s[t] = pb1[t]; b2s[t] = pb2[t]; }
  if (t < 128) b3s[t] = pb3[t];
  __syncthreads();
  int wid = t >> 6, lane = t & 63;
  int ebase = blockIdx.x * 128 + wid * 32;   // 128 edges/block, one wave per edge, 32 edges/wave
  for (int it = 0; it < 32; ++it) {
    int e = ebase + it;
    // bf16 copy of pred row (coalesced 16B/lane)
    const float* pr = pred + (size_t)e * 512 + lane * 8;
    float4 pA = *(const float4*)pr;
    float4 pB = *(const float4*)(pr + 4);
    u16x8 o;
    o[0] = f2bf(pA.x); o[1] = f2bf(pA.y); o[2] = f2bf(pA.z); o[3] = f2bf(pA.w);
    o[4] = f2bf(pB.x); o[5] = f2bf(pB.y); o[6] = f2bf(pB.z); o[7] = f2bf(pB.w);
    *(u16x8*)(X + (size_t)e * 512 + lane * 8) = o;
    // edge (i,j): ii=repeat(outer), jj=tile(inner), diagonal removed
    int i = e / nm1;
    int r = e - i * nm1;
    int j = r + (r >= i ? 1 : 0);
    float dx = centroid[i * 3 + 0] - centroid[j * 3 + 0];
    float dy = centroid[i * 3 + 1] - centroid[j * 3 + 1];
    float dist = sqrtf(dx * dx + dy * dy);
    float inv = 1.0f / dist;
    // layer1 (5->64): lane owns h1[lane]
    float h1 = w1[0 * 64 + lane] * dx + w1[1 * 64 + lane] * dy + w1[2 * 64 + lane] * dist
             + w1[3 * 64 + lane] * (dx * inv) + w1[4 * 64 + lane] * (dy * inv) + b1s[lane];
    h1 = fmaxf(h1, 0.0f);
    // layer2 (64->64) via wave shuffles (race-free by construction)
    float h2 = b2s[lane];
#pragma unroll
    for (int k = 0; k < 64; ++k) h2 += __shfl(h1, k) * w2[k * 64 + lane];
    h2 = fmaxf(h2, 0.0f);
    // layer3 (64->128), linear
    float o0 = b3s[lane], o1 = b3s[64 + lane];
#pragma unroll
    for (int k = 0; k < 64; ++k) {
      float hk = __shfl(h2, k);
      o0 += hk * w3[k * 128 + lane];
      o1 += hk * w3[k * 128 + 64 + lane];
    }
    pos[(size_t)e * 128 + lane] = f2bf(o0);
    pos[(size_t)e * 128 + 64 + lane] = f2bf(o1);
  }
}

// ---------------- GEMM C(M,512) = relu(A(M,K) @ W(K,512) + bias), f32 accum
// m97 structure: 128x128 tile, BK=64, 4 waves (2x2).
// A: up to 3 concatenated-K segments (kt<s0 -> A0, kt<s1 -> A1, else A2).
//   aF32=0: A is bf16, staged via global_load_lds width 16.
//   aF32=1: A is f32,  reg-staged with on-the-fly f32->bf16 convert.
// Cout: outF32=1 -> float* (final outputs), else bf16 ushort* (hidden activations).
__global__ __launch_bounds__(256) void gemm_bias_relu(
    const void* __restrict__ A0, int lda0,
    const void* __restrict__ A1, int lda1,
    const void* __restrict__ A2, int lda2,
    int s0, int s1, int aF32,
    const ushort_t* __restrict__ Bt, const float* __restrict__ bias,
    void* __restrict__ Cout, int outF32, int K)
{
  __shared__ ushort_t As[128 * 64];
  __shared__ ushort_t Bs[128 * 64];
  int bid = blockIdx.x;
  int cpx = gridDim.x >> 3;                    // grid % 8 == 0 (2040)
  int swz = (bid & 7) * cpx + (bid >> 3);      // XCD-aware swizzle (bijective: 2040 % 8 == 0)
  int mt = swz >> 2, nt = swz & 3;             // 4 n-tiles; consecutive swz share mt
  int m0 = mt << 7, n0 = nt << 7;
  int t = threadIdx.x;
  int lane = t & 63, wid = t >> 6;
  int wm = wid >> 1, wn = wid & 1;             // wave -> 64x64 quadrant
  f32x4 acc[4][4];
  f32x4 zero = {0.0f, 0.0f, 0.0f, 0.0f};
#pragma unroll
  for (int a_ = 0; a_ < 4; ++a_)
#pragma unroll
    for (int b_ = 0; b_ < 4; ++b_) acc[a_][b_] = zero;

  for (int kt = 0; kt < K; kt += 64) {
    const void* Ab; int ldaA; int kin;
    if (kt < s0)      { Ab = A0; ldaA = lda0; kin = kt; }
    else if (kt < s1) { Ab = A1; ldaA = lda1; kin = kt - s0; }
    else              { Ab = A2; ldaA = lda2; kin = kt - s1; }
    if (aF32) {
      // reg-staged: 128 rows x 64 cols, f32 -> bf16. thread t: row t>>1, 32 cols.
      const float* Af = (const float*)Ab;
      int rr = t >> 1, cc0 = (t & 1) << 5;
      const float* g = Af + (size_t)(m0 + rr) * ldaA + kin + cc0;
      ushort_t* ldst = As + rr * 64 + cc0;
#pragma unroll
      for (int i = 0; i < 4; ++i) {
        float4 v0 = *(const float4*)(g + i * 8);
        float4 v1 = *(const float4*)(g + i * 8 + 4);
        u16x8 o;
        o[0] = f2bf(v0.x); o[1] = f2bf(v0.y); o[2] = f2bf(v0.z); o[3] = f2bf(v0.w);
        o[4] = f2bf(v1.x); o[5] = f2bf(v1.y); o[6] = f2bf(v1.z); o[7] = f2bf(v1.w);
        *(u16x8*)(ldst + i * 8) = o;
      }
    } else {
      const ushort_t* Ah = (const ushort_t*)Ab;
#pragma unroll
      for (int i = 0; i < 4; ++i) {            // stage A tile: 128 rows x 64 bf16
        int ch = i * 256 + t;
        int rr = ch >> 3, cc = (ch & 7) << 3;
        const ushort_t* g = Ah + (size_t)(m0 + rr) * ldaA + kin + cc;
        __builtin_amdgcn_global_load_lds((const GLOBAL_AS void*)g,
                                         (LDS_AS void*)(As + ch * 8), 16, 0, 0);
      }
    }
#pragma unroll
    for (int i = 0; i < 4; ++i) {              // stage B^T tile: 128 n-rows x 64 bf16
      int ch = i * 256 + t;
      int rr = ch >> 3, cc = (ch & 7) << 3;
      const ushort_t* g = Bt + (size_t)(n0 + rr) * K + kt + cc;
      __builtin_amdgcn_global_load_lds((const GLOBAL_AS void*)g,
                                       (LDS_AS void*)(Bs + ch * 8), 16, 0, 0);
    }
    __syncthreads();                            // drains vmcnt/lgkmcnt before barrier
#pragma unroll
    for (int kk = 0; kk < 64; kk += 32) {
      int ko = kk + (lane >> 4) * 8;
      short8 a[4], b[4];
#pragma unroll
      for (int m_ = 0; m_ < 4; ++m_)
        a[m_] = *(const short8*)(As + (wm * 64 + m_ * 16 + (lane & 15)) * 64 + ko);
#pragma unroll
      for (int n_ = 0; n_ < 4; ++n_)
        b[n_] = *(const short8*)(Bs + (wn * 64 + n_ * 16 + (lane & 15)) * 64 + ko);
#pragma unroll
      for (int m_ = 0; m_ < 4; ++m_)
#pragma unroll
        for (int n_ = 0; n_ < 4; ++n_)
          acc[m_][n_] = __builtin_amdgcn_mfma_f32_16x16x32_bf16(a[m_], b[n_], acc[m_][n_], 0, 0, 0);
    }
    __syncthreads();
  }
  // epilogue: C/D layout col=lane&15, row=(lane>>4)*4+jj (m89-verified)
  int colg = lane & 15, rowg = (lane >> 4) << 2;
  float* C32 = (float*)Cout;
  ushort_t* C16 = (ushort_t*)Cout;
#pragma unroll
  for (int n_ = 0; n_ < 4; ++n_) {
    int col = n0 + wn * 64 + n_ * 16 + colg;
    float bv = bias[col];
#pragma unroll
    for (int m_ = 0; m_ < 4; ++m_) {
      int row = m0 + wm * 64 + m_ * 16 + rowg;
#pragma unroll
      for (int jj = 0; jj < 4; ++jj) {
        float v = fmaxf(acc[m_][n_][jj] + bv, 0.0f);
        if (outF32) C32[(size_t)(row + jj) * 512 + col] = v;
        else        C16[(size_t)(row + jj) * 512 + col] = f2bf(v);
      }
    }
  }
}

extern "C" void kernel_launch(void* const* d_in, const int* in_sizes, int n_in,
                              void* d_out, int out_size, void* d_ws, size_t ws_size,
                              hipStream_t stream) {
  (void)n_in; (void)out_size; (void)ws_size;
  const float* pred = (const float*)d_in[1];
  const float* centroid = (const float*)d_in[4];
  // weight order: s1, s2, p1, p2, c1, c2, l1, l2
  const float* W[8] = { (const float*)d_in[5],  (const float*)d_in[7],  (const float*)d_in[9],
                        (const float*)d_in[11], (const float*)d_in[13], (const float*)d_in[15],
                        (const float*)d_in[17], (const float*)d_in[19] };
  const float* Bv[8] = { (const float*)d_in[6],  (const float*)d_in[8],  (const float*)d_in[10],
                         (const float*)d_in[12], (const float*)d_in[14], (const float*)d_in[16],
                         (const float*)d_in[18], (const float*)d_in[20] };
  int Kd[8] = {512, 512, 640, 512, 512, 512, 1536, 512};
  const float* pos_w1 = (const float*)d_in[21]; const float* pos_b1 = (const float*)d_in[22];
  const float* pos_w2 = (const float*)d_in[23]; const float* pos_b2 = (const float*)d_in[24];
  const float* pos_w3 = (const float*)d_in[25]; const float* pos_b3 = (const float*)d_in[26];

  int E = in_sizes[1] / 512;       // 65280
  int n = in_sizes[4] / 3;         // 256

  // ---- workspace: ONLY Wt (5.4MB) + X (66.8MB) ~= 72.3MB.
  char* ws = (char*)d_ws;
  size_t off = 0;
  auto alloc = [&](size_t bytes) -> void* {
    void* p = ws + off;
    off = (off + bytes + 255) & ~(size_t)255;
    return p;
  };
  ushort_t* Wt[8];
  for (int i = 0; i < 8; ++i) Wt[i] = (ushort_t*)alloc((size_t)Kd[i] * 512 * 2);
  ushort_t* X = (ushort_t*)alloc((size_t)E * 512 * 2);   // bf16 pred; later reused as link hidden

  // ---- d_out is FLOAT32 (reference output dtype). 4 slots of E*512 f32.
  float* outF = (float*)d_out;
  size_t S = (size_t)E * 512;
  float* out_link = outF;            // slot 0 (first 99MB doubles as bf16 scratch early on)
  float* out_sup  = outF + S;        // slot 1
  float* out_prox = outF + 2 * S;    // slot 2
  float* out_comp = outF + 3 * S;    // slot 3
  // bf16 scratch parked inside slot 0's bytes (133.7MB): pos (16.7MB) + H_branch (66.9MB).
  // Both are dead before link L2 writes slot 0.
  ushort_t* pos = (ushort_t*)d_out;
  ushort_t* Hb  = (ushort_t*)((char*)d_out + (size_t)32 * 1024 * 1024);
  ushort_t* Hl  = X;                 // link hidden reuses X region (X dead after comp L1)

  TransArgs ta;
  int nblk = 0;
  for (int i = 0; i < 8; ++i) {
    ta.src[i] = W[i]; ta.dst[i] = Wt[i]; ta.K[i] = Kd[i];
    ta.blk0[i] = nblk;
    nblk += (Kd[i] >> 6) * 8;          // (K/64) x (512/64) tiles
  }
  ta.blk0[8] = nblk;
  hipLaunchKernelGGL(transpose_weights, dim3(nblk), dim3(256), 0, stream, ta);
  hipLaunchKernelGGL(prep_kernel, dim3(E / 128), dim3(256), 0, stream,
                     pred, centroid, pos_w1, pos_b1, pos_w2, pos_b2, pos_w3, pos_b3,
                     X, pos, n - 1);

  dim3 g(E / 128 * 4), blk(256);
  const void* Z = nullptr;
  // proximity FIRST (pos scratch lives in slot 0; harmless, but keep ordering tight)
  hipLaunchKernelGGL(gemm_bias_relu, g, blk, 0, stream,
                     (const void*)X, 512, (const void*)pos, 128, Z, 0, 512, 640, 0,
                     Wt[2], Bv[2], (void*)Hb, 0, 640);
  hipLaunchKernelGGL(gemm_bias_relu, g, blk, 0, stream,
                     (const void*)Hb, 512, Z, 0, Z, 0, 512, 512, 0,
                     Wt[3], Bv[3], (void*)out_prox, 1, 512);
  // support
  hipLaunchKernelGGL(gemm_bias_relu, g, blk, 0, stream,
                     (const void*)X, 512, Z, 0, Z, 0, 512, 512, 0,
                     Wt[0], Bv[0], (void*)Hb, 0, 512);
  hipLaunchKernelGGL(gemm_bias_relu, g, blk, 0, stream,
                     (const void*)Hb, 512, Z, 0, Z, 0, 512, 512, 0,
                     Wt[1], Bv[1], (void*)out_sup, 1, 512);
  // comp
  hipLaunchKernelGGL(gemm_bias_relu, g, blk, 0, stream,
                     (const void*)X, 512, Z, 0, Z, 0, 512, 512, 0,
                     Wt[4], Bv[4], (void*)Hb, 0, 512);
  hipLaunchKernelGGL(gemm_bias_relu, g, blk, 0, stream,
                     (const void*)Hb, 512, Z, 0, Z, 0, 512, 512, 0,
                     Wt[5], Bv[5], (void*)out_comp, 1, 512);
  // link: A = [support | proximity | comp] (f32, reg-staged convert); hidden -> X region
  hipLaunchKernelGGL(gemm_bias_relu, g, blk, 0, stream,
                     (const void*)out_sup, 512, (const void*)out_prox, 512,
                     (const void*)out_comp, 512, 512, 1024, 1,
                     Wt[6], Bv[6], (void*)Hl, 0, 1536);
  hipLaunchKernelGGL(gemm_bias_relu, g, blk, 0, stream,
                     (const void*)Hl, 512, Z, 0, Z, 0, 512, 512, 0,
                     Wt[7], Bv[7], (void*)out_link, 1, 512);
}

// Round 5
// 829.965 us; speedup vs baseline: 1.3063x; 1.3063x over previous
//
#include <hip/hip_runtime.h>
#include <stdint.h>

typedef unsigned short ushort_t;
typedef __attribute__((ext_vector_type(8))) short short8;
typedef __attribute__((ext_vector_type(8))) unsigned short u16x8;
typedef __attribute__((ext_vector_type(4))) float f32x4;

#define GLOBAL_AS __attribute__((address_space(1)))
#define LDS_AS __attribute__((address_space(3)))

__device__ __forceinline__ ushort_t f2bf(float f) {
  union { float f; uint32_t u; } v; v.f = f;
  uint32_t u = v.u;
  u += 0x7FFFu + ((u >> 16) & 1u);   // round-to-nearest-even
  return (ushort_t)(u >> 16);
}

// XOR swizzle for [R][64] bf16 LDS tiles (128B rows): kills the 32-way
// same-bank column conflict on ds_read_b128 (G4). 16B-granular, bijective.
__device__ __forceinline__ int swz(int row, int byteInRow) {
  return (row * 128 + byteInRow) ^ ((row & 7) << 4);
}

// ---------------- weight transpose + bf16 cast: dst[n][k] = bf16(src[k][n]); fout = 512 always
struct TransArgs {
  const float* src[8];
  ushort_t* dst[8];
  int K[8];
  int blk0[9];
};

__global__ __launch_bounds__(256) void transpose_weights(TransArgs ta) {
  __shared__ float tile[64 * 65];
  int b = blockIdx.x;
  int mi = 0;
#pragma unroll
  for (int i = 1; i < 8; ++i) if (b >= ta.blk0[i]) mi = i;
  const float* src = ta.src[mi];
  ushort_t* dst = ta.dst[mi];
  int K = ta.K[mi];
  int rel = b - ta.blk0[mi];
  int ktiles = K >> 6;
  int k0 = (rel % ktiles) << 6;
  int n0 = (rel / ktiles) << 6;
  int t = threadIdx.x;
#pragma unroll
  for (int i = 0; i < 16; ++i) {
    int idx = i * 256 + t;
    int r = idx >> 6, c = idx & 63;
    tile[r * 65 + c] = src[(size_t)(k0 + r) * 512 + (n0 + c)];
  }
  __syncthreads();
#pragma unroll
  for (int i = 0; i < 16; ++i) {
    int idx = i * 256 + t;
    int r = idx >> 6, c = idx & 63;          // r: n-row, c: k-col
    dst[(size_t)(n0 + r) * K + (k0 + c)] = f2bf(tile[c * 65 + r]);
  }
}

// ---------------- prep: X[e][0:512]=bf16(pred); pos[e][0:128] = 3-layer FCN via MFMA.
// Block = 256 thr (4 waves) = 128 edges. Layer1 per-lane -> LDS h1[128][64];
// layer2/3 on matrix pipe with LDS-resident transposed weights.
__global__ __launch_bounds__(256) void prep_kernel(
    const float* __restrict__ pred, const float* __restrict__ centroid,
    const float* __restrict__ pw1, const float* __restrict__ pb1,
    const float* __restrict__ pw2, const float* __restrict__ pb2,
    const float* __restrict__ pw3, const float* __restrict__ pb3,
    ushort_t* __restrict__ X, ushort_t* __restrict__ pos, int nm1)
{
  __shared__ ushort_t h1s[128 * 64];     // swizzled [128][64]
  __shared__ ushort_t h2s[128 * 64];     // swizzled [128][64]
  __shared__ ushort_t w2t[64 * 64];      // swizzled [n=64][k=64], w2t[n][k]=w2[k][n]
  __shared__ ushort_t w3t[128 * 64];     // swizzled [n=128][k=64]
  __shared__ float w1s[5 * 64];
  __shared__ float b1s[64], b2s[64], b3s[128];
  int t = threadIdx.x;
  // ---- stage weights (coalesced reads; swizzled LDS writes)
  for (int idx = t; idx < 64 * 64; idx += 256) {
    int k = idx >> 6, n = idx & 63;               // consecutive t -> consecutive n
    *(ushort_t*)((char*)w2t + swz(n, k * 2)) = f2bf(pw2[idx]);
  }
  for (int idx = t; idx < 64 * 128; idx += 256) {
    int k = idx >> 7, n = idx & 127;
    *(ushort_t*)((char*)w3t + swz(n, k * 2)) = f2bf(pw3[idx]);
  }
  for (int i = t; i < 5 * 64; i += 256) w1s[i] = pw1[i];
  if (t < 64) { b1s[t] = pb1[t]; b2s[t] = pb2[t]; }
  if (t < 128) b3s[t] = pb3[t];
  __syncthreads();   // RACE FIX (round 4): w1s/b1s are read by ALL waves in
                     // stage 1 but written by threads of other waves; without
                     // this barrier waves 1-3 could read stale LDS.

  int wid = t >> 6, lane = t & 63;
  int ebase = blockIdx.x * 128 + wid * 32;   // wave owns rows [wid*32, wid*32+32)
  // ---- stage 1: X cast + layer1 (per-lane, h1[row][lane])
  for (int it = 0; it < 32; ++it) {
    int e = ebase + it;
    const float* pr = pred + (size_t)e * 512 + lane * 8;
    float4 pA = *(const float4*)pr;
    float4 pB = *(const float4*)(pr + 4);
    u16x8 o;
    o[0] = f2bf(pA.x); o[1] = f2bf(pA.y); o[2] = f2bf(pA.z); o[3] = f2bf(pA.w);
    o[4] = f2bf(pB.x); o[5] = f2bf(pB.y); o[6] = f2bf(pB.z); o[7] = f2bf(pB.w);
    *(u16x8*)(X + (size_t)e * 512 + lane * 8) = o;
    // edge (i,j): ii=repeat(outer), jj=tile(inner), diagonal removed
    int i = e / nm1;
    int r = e - i * nm1;
    int j = r + (r >= i ? 1 : 0);
    float dx = centroid[i * 3 + 0] - centroid[j * 3 + 0];
    float dy = centroid[i * 3 + 1] - centroid[j * 3 + 1];
    float dist = sqrtf(dx * dx + dy * dy);
    float inv = 1.0f / dist;
    float h1 = w1s[0 * 64 + lane] * dx + w1s[1 * 64 + lane] * dy + w1s[2 * 64 + lane] * dist
             + w1s[3 * 64 + lane] * (dx * inv) + w1s[4 * 64 + lane] * (dy * inv) + b1s[lane];
    h1 = fmaxf(h1, 0.0f);
    int row = wid * 32 + it;
    *(ushort_t*)((char*)h1s + swz(row, lane * 2)) = f2bf(h1);
  }
  __syncthreads();

  int colg = lane & 15, rowg = (lane >> 4) << 2;
  int ko_lane = (lane >> 4) * 8;            // k sub-offset per 16-lane group
  // ---- layer2: h2(32x64 per wave) = relu(h1 @ w2), K=64
  {
    f32x4 acc[2][4];
    f32x4 zero = {0.0f, 0.0f, 0.0f, 0.0f};
#pragma unroll
    for (int m_ = 0; m_ < 2; ++m_)
#pragma unroll
      for (int n_ = 0; n_ < 4; ++n_) acc[m_][n_] = zero;
#pragma unroll
    for (int kk = 0; kk < 2; ++kk) {
      int ko = kk * 32 + ko_lane;
      short8 a[2], b[4];
#pragma unroll
      for (int m_ = 0; m_ < 2; ++m_)
        a[m_] = *(const short8*)((const char*)h1s + swz(wid * 32 + m_ * 16 + colg, ko * 2));
#pragma unroll
      for (int n_ = 0; n_ < 4; ++n_)
        b[n_] = *(const short8*)((const char*)w2t + swz(n_ * 16 + colg, ko * 2));
#pragma unroll
      for (int m_ = 0; m_ < 2; ++m_)
#pragma unroll
        for (int n_ = 0; n_ < 4; ++n_)
          acc[m_][n_] = __builtin_amdgcn_mfma_f32_16x16x32_bf16(a[m_], b[n_], acc[m_][n_], 0, 0, 0);
    }
#pragma unroll
    for (int n_ = 0; n_ < 4; ++n_) {
      int col = n_ * 16 + colg;
      float bv = b2s[col];
#pragma unroll
      for (int m_ = 0; m_ < 2; ++m_) {
        int row = wid * 32 + m_ * 16 + rowg;
#pragma unroll
        for (int jj = 0; jj < 4; ++jj) {
          float v = fmaxf(acc[m_][n_][jj] + bv, 0.0f);
          *(ushort_t*)((char*)h2s + swz(row + jj, col * 2)) = f2bf(v);
        }
      }
    }
  }
  __syncthreads();   // cross-lane h2 handoff
  // ---- layer3: pos(32x128 per wave) = h2 @ w3 (linear), K=64
  {
    f32x4 acc[2][8];
    f32x4 zero = {0.0f, 0.0f, 0.0f, 0.0f};
#pragma unroll
    for (int m_ = 0; m_ < 2; ++m_)
#pragma unroll
      for (int n_ = 0; n_ < 8; ++n_) acc[m_][n_] = zero;
#pragma unroll
    for (int kk = 0; kk < 2; ++kk) {
      int ko = kk * 32 + ko_lane;
      short8 a[2], b[8];
#pragma unroll
      for (int m_ = 0; m_ < 2; ++m_)
        a[m_] = *(const short8*)((const char*)h2s + swz(wid * 32 + m_ * 16 + colg, ko * 2));
#pragma unroll
      for (int n_ = 0; n_ < 8; ++n_)
        b[n_] = *(const short8*)((const char*)w3t + swz(n_ * 16 + colg, ko * 2));
#pragma unroll
      for (int m_ = 0; m_ < 2; ++m_)
#pragma unroll
        for (int n_ = 0; n_ < 8; ++n_)
          acc[m_][n_] = __builtin_amdgcn_mfma_f32_16x16x32_bf16(a[m_], b[n_], acc[m_][n_], 0, 0, 0);
    }
#pragma unroll
    for (int n_ = 0; n_ < 8; ++n_) {
      int col = n_ * 16 + colg;
      float bv = b3s[col];
#pragma unroll
      for (int m_ = 0; m_ < 2; ++m_) {
        int row = wid * 32 + m_ * 16 + rowg;
#pragma unroll
        for (int jj = 0; jj < 4; ++jj) {
          int e = blockIdx.x * 128 + row + jj;
          pos[(size_t)e * 128 + col] = f2bf(acc[m_][n_][jj] + bv);
        }
      }
    }
  }
}

// ---------------- GEMM C(M,512) = relu(A(M,K) @ W(K,512) + bias), f32 accum
// m97 structure: 128x128 tile, BK=64, 4 waves (2x2).
// A: up to 3 concatenated-K segments (kt<s0 -> A0, kt<s1 -> A1, else A2).
//   aF32=0: A is bf16, staged via global_load_lds width 16.
//   aF32=1: A is f32,  reg-staged with on-the-fly f32->bf16 convert.
// Cout: outF32=1 -> float* (final outputs), else bf16 ushort* (hidden activations).
__global__ __launch_bounds__(256) void gemm_bias_relu(
    const void* __restrict__ A0, int lda0,
    const void* __restrict__ A1, int lda1,
    const void* __restrict__ A2, int lda2,
    int s0, int s1, int aF32,
    const ushort_t* __restrict__ Bt, const float* __restrict__ bias,
    void* __restrict__ Cout, int outF32, int K)
{
  __shared__ ushort_t As[128 * 64];
  __shared__ ushort_t Bs[128 * 64];
  int bid = blockIdx.x;
  int cpx = gridDim.x >> 3;                    // grid % 8 == 0 (2040)
  int swzb = (bid & 7) * cpx + (bid >> 3);     // XCD-aware swizzle (bijective: 2040 % 8 == 0)
  int mt = swzb >> 2, nt = swzb & 3;           // 4 n-tiles; consecutive swz share mt
  int m0 = mt << 7, n0 = nt << 7;
  int t = threadIdx.x;
  int lane = t & 63, wid = t >> 6;
  int wm = wid >> 1, wn = wid & 1;             // wave -> 64x64 quadrant
  f32x4 acc[4][4];
  f32x4 zero = {0.0f, 0.0f, 0.0f, 0.0f};
#pragma unroll
  for (int a_ = 0; a_ < 4; ++a_)
#pragma unroll
    for (int b_ = 0; b_ < 4; ++b_) acc[a_][b_] = zero;

  for (int kt = 0; kt < K; kt += 64) {
    const void* Ab; int ldaA; int kin;
    if (kt < s0)      { Ab = A0; ldaA = lda0; kin = kt; }
    else if (kt < s1) { Ab = A1; ldaA = lda1; kin = kt - s0; }
    else              { Ab = A2; ldaA = lda2; kin = kt - s1; }
    if (aF32) {
      // reg-staged: 128 rows x 64 cols, f32 -> bf16. thread t: row t>>1, 32 cols.
      const float* Af = (const float*)Ab;
      int rr = t >> 1, cc0 = (t & 1) << 5;
      const float* g = Af + (size_t)(m0 + rr) * ldaA + kin + cc0;
      ushort_t* ldst = As + rr * 64 + cc0;
#pragma unroll
      for (int i = 0; i < 4; ++i) {
        float4 v0 = *(const float4*)(g + i * 8);
        float4 v1 = *(const float4*)(g + i * 8 + 4);
        u16x8 o;
        o[0] = f2bf(v0.x); o[1] = f2bf(v0.y); o[2] = f2bf(v0.z); o[3] = f2bf(v0.w);
        o[4] = f2bf(v1.x); o[5] = f2bf(v1.y); o[6] = f2bf(v1.z); o[7] = f2bf(v1.w);
        *(u16x8*)(ldst + i * 8) = o;
      }
    } else {
      const ushort_t* Ah = (const ushort_t*)Ab;
#pragma unroll
      for (int i = 0; i < 4; ++i) {            // stage A tile: 128 rows x 64 bf16
        int ch = i * 256 + t;
        int rr = ch >> 3, cc = (ch & 7) << 3;
        const ushort_t* g = Ah + (size_t)(m0 + rr) * ldaA + kin + cc;
        __builtin_amdgcn_global_load_lds((const GLOBAL_AS void*)g,
                                         (LDS_AS void*)(As + ch * 8), 16, 0, 0);
      }
    }
#pragma unroll
    for (int i = 0; i < 4; ++i) {              // stage B^T tile: 128 n-rows x 64 bf16
      int ch = i * 256 + t;
      int rr = ch >> 3, cc = (ch & 7) << 3;
      const ushort_t* g = Bt + (size_t)(n0 + rr) * K + kt + cc;
      __builtin_amdgcn_global_load_lds((const GLOBAL_AS void*)g,
                                       (LDS_AS void*)(Bs + ch * 8), 16, 0, 0);
    }
    __syncthreads();                            // drains vmcnt/lgkmcnt before barrier
#pragma unroll
    for (int kk = 0; kk < 64; kk += 32) {
      int ko = kk + (lane >> 4) * 8;
      short8 a[4], b[4];
#pragma unroll
      for (int m_ = 0; m_ < 4; ++m_)
        a[m_] = *(const short8*)(As + (wm * 64 + m_ * 16 + (lane & 15)) * 64 + ko);
#pragma unroll
      for (int n_ = 0; n_ < 4; ++n_)
        b[n_] = *(const short8*)(Bs + (wn * 64 + n_ * 16 + (lane & 15)) * 64 + ko);
#pragma unroll
      for (int m_ = 0; m_ < 4; ++m_)
#pragma unroll
        for (int n_ = 0; n_ < 4; ++n_)
          acc[m_][n_] = __builtin_amdgcn_mfma_f32_16x16x32_bf16(a[m_], b[n_], acc[m_][n_], 0, 0, 0);
    }
    __syncthreads();
  }
  // epilogue: C/D layout col=lane&15, row=(lane>>4)*4+jj (m89-verified)
  int colg = lane & 15, rowg = (lane >> 4) << 2;
  float* C32 = (float*)Cout;
  ushort_t* C16 = (ushort_t*)Cout;
#pragma unroll
  for (int n_ = 0; n_ < 4; ++n_) {
    int col = n0 + wn * 64 + n_ * 16 + colg;
    float bv = bias[col];
#pragma unroll
    for (int m_ = 0; m_ < 4; ++m_) {
      int row = m0 + wm * 64 + m_ * 16 + rowg;
#pragma unroll
      for (int jj = 0; jj < 4; ++jj) {
        float v = fmaxf(acc[m_][n_][jj] + bv, 0.0f);
        if (outF32) C32[(size_t)(row + jj) * 512 + col] = v;
        else        C16[(size_t)(row + jj) * 512 + col] = f2bf(v);
      }
    }
  }
}

extern "C" void kernel_launch(void* const* d_in, const int* in_sizes, int n_in,
                              void* d_out, int out_size, void* d_ws, size_t ws_size,
                              hipStream_t stream) {
  (void)n_in; (void)out_size; (void)ws_size;
  const float* pred = (const float*)d_in[1];
  const float* centroid = (const float*)d_in[4];
  // weight order: s1, s2, p1, p2, c1, c2, l1, l2
  const float* W[8] = { (const float*)d_in[5],  (const float*)d_in[7],  (const float*)d_in[9],
                        (const float*)d_in[11], (const float*)d_in[13], (const float*)d_in[15],
                        (const float*)d_in[17], (const float*)d_in[19] };
  const float* Bv[8] = { (const float*)d_in[6],  (const float*)d_in[8],  (const float*)d_in[10],
                         (const float*)d_in[12], (const float*)d_in[14], (const float*)d_in[16],
                         (const float*)d_in[18], (const float*)d_in[20] };
  int Kd[8] = {512, 512, 640, 512, 512, 512, 1536, 512};
  const float* pos_w1 = (const float*)d_in[21]; const float* pos_b1 = (const float*)d_in[22];
  const float* pos_w2 = (const float*)d_in[23]; const float* pos_b2 = (const float*)d_in[24];
  const float* pos_w3 = (const float*)d_in[25]; const float* pos_b3 = (const float*)d_in[26];

  int E = in_sizes[1] / 512;       // 65280
  int n = in_sizes[4] / 3;         // 256

  // ---- workspace: ONLY Wt (5.4MB) + X (66.8MB) ~= 72.3MB.
  char* ws = (char*)d_ws;
  size_t off = 0;
  auto alloc = [&](size_t bytes) -> void* {
    void* p = ws + off;
    off = (off + bytes + 255) & ~(size_t)255;
    return p;
  };
  ushort_t* Wt[8];
  for (int i = 0; i < 8; ++i) Wt[i] = (ushort_t*)alloc((size_t)Kd[i] * 512 * 2);
  ushort_t* X = (ushort_t*)alloc((size_t)E * 512 * 2);   // bf16 pred; later reused as link hidden

  // ---- d_out is FLOAT32 (reference output dtype). 4 slots of E*512 f32.
  float* outF = (float*)d_out;
  size_t S = (size_t)E * 512;
  float* out_link = outF;            // slot 0 (first 99MB doubles as bf16 scratch early on)
  float* out_sup  = outF + S;        // slot 1
  float* out_prox = outF + 2 * S;    // slot 2
  float* out_comp = outF + 3 * S;    // slot 3
  // bf16 scratch parked inside slot 0's bytes (133.7MB): pos (16.7MB) + H_branch (66.9MB).
  // Both are dead before link L2 writes slot 0.
  ushort_t* pos = (ushort_t*)d_out;
  ushort_t* Hb  = (ushort_t*)((char*)d_out + (size_t)32 * 1024 * 1024);
  ushort_t* Hl  = X;                 // link hidden reuses X region (X dead after comp L1)

  TransArgs ta;
  int nblk = 0;
  for (int i = 0; i < 8; ++i) {
    ta.src[i] = W[i]; ta.dst[i] = Wt[i]; ta.K[i] = Kd[i];
    ta.blk0[i] = nblk;
    nblk += (Kd[i] >> 6) * 8;          // (K/64) x (512/64) tiles
  }
  ta.blk0[8] = nblk;
  hipLaunchKernelGGL(transpose_weights, dim3(nblk), dim3(256), 0, stream, ta);
  hipLaunchKernelGGL(prep_kernel, dim3(E / 128), dim3(256), 0, stream,
                     pred, centroid, pos_w1, pos_b1, pos_w2, pos_b2, pos_w3, pos_b3,
                     X, pos, n - 1);

  dim3 g(E / 128 * 4), blk(256);
  const void* Z = nullptr;
  // proximity FIRST (pos scratch lives in slot 0)
  hipLaunchKernelGGL(gemm_bias_relu, g, blk, 0, stream,
                     (const void*)X, 512, (const void*)pos, 128, Z, 0, 512, 640, 0,
                     Wt[2], Bv[2], (void*)Hb, 0, 640);
  hipLaunchKernelGGL(gemm_bias_relu, g, blk, 0, stream,
                     (const void*)Hb, 512, Z, 0, Z, 0, 512, 512, 0,
                     Wt[3], Bv[3], (void*)out_prox, 1, 512);
  // support
  hipLaunchKernelGGL(gemm_bias_relu, g, blk, 0, stream,
                     (const void*)X, 512, Z, 0, Z, 0, 512, 512, 0,
                     Wt[0], Bv[0], (void*)Hb, 0, 512);
  hipLaunchKernelGGL(gemm_bias_relu, g, blk, 0, stream,
                     (const void*)Hb, 512, Z, 0, Z, 0, 512, 512, 0,
                     Wt[1], Bv[1], (void*)out_sup, 1, 512);
  // comp
  hipLaunchKernelGGL(gemm_bias_relu, g, blk, 0, stream,
                     (const void*)X, 512, Z, 0, Z, 0, 512, 512, 0,
                     Wt[4], Bv[4], (void*)Hb, 0, 512);
  hipLaunchKernelGGL(gemm_bias_relu, g, blk, 0, stream,
                     (const void*)Hb, 512, Z, 0, Z, 0, 512, 512, 0,
                     Wt[5], Bv[5], (void*)out_comp, 1, 512);
  // link: A = [support | proximity | comp] (f32, reg-staged convert); hidden -> X region
  hipLaunchKernelGGL(gemm_bias_relu, g, blk, 0, stream,
                     (const void*)out_sup, 512, (const void*)out_prox, 512,
                     (const void*)out_comp, 512, 512, 1024, 1,
                     Wt[6], Bv[6], (void*)Hl, 0, 1536);
  hipLaunchKernelGGL(gemm_bias_relu, g, blk, 0, stream,
                     (const void*)Hl, 512, Z, 0, Z, 0, 512, 512, 0,
                     Wt[7], Bv[7], (void*)out_link, 1, 512);
}

// Round 6
// 807.403 us; speedup vs baseline: 1.3428x; 1.0279x over previous
//
#include <hip/hip_runtime.h>
#include <stdint.h>

typedef unsigned short ushort_t;
typedef __attribute__((ext_vector_type(8))) short short8;
typedef __attribute__((ext_vector_type(8))) unsigned short u16x8;
typedef __attribute__((ext_vector_type(4))) float f32x4;

#define GLOBAL_AS __attribute__((address_space(1)))
#define LDS_AS __attribute__((address_space(3)))

__device__ __forceinline__ ushort_t f2bf(float f) {
  union { float f; uint32_t u; } v; v.f = f;
  uint32_t u = v.u;
  u += 0x7FFFu + ((u >> 16) & 1u);   // round-to-nearest-even
  return (ushort_t)(u >> 16);
}

// XOR swizzle for [R][64] bf16 LDS tiles (128B rows): kills the 32-way
// same-bank column conflict on ds_read_b128 (G4). 16B-granular, bijective.
__device__ __forceinline__ int swz(int row, int byteInRow) {
  return (row * 128 + byteInRow) ^ ((row & 7) << 4);
}

// ---------------- weight transpose + bf16 cast: dst[n][k] = bf16(src[k][n]); fout = 512 always
struct TransArgs {
  const float* src[8];
  ushort_t* dst[8];
  int K[8];
  int blk0[9];
};

__global__ __launch_bounds__(256) void transpose_weights(TransArgs ta) {
  __shared__ float tile[64 * 65];
  int b = blockIdx.x;
  int mi = 0;
#pragma unroll
  for (int i = 1; i < 8; ++i) if (b >= ta.blk0[i]) mi = i;
  const float* src = ta.src[mi];
  ushort_t* dst = ta.dst[mi];
  int K = ta.K[mi];
  int rel = b - ta.blk0[mi];
  int ktiles = K >> 6;
  int k0 = (rel % ktiles) << 6;
  int n0 = (rel / ktiles) << 6;
  int t = threadIdx.x;
#pragma unroll
  for (int i = 0; i < 16; ++i) {
    int idx = i * 256 + t;
    int r = idx >> 6, c = idx & 63;
    tile[r * 65 + c] = src[(size_t)(k0 + r) * 512 + (n0 + c)];
  }
  __syncthreads();
#pragma unroll
  for (int i = 0; i < 16; ++i) {
    int idx = i * 256 + t;
    int r = idx >> 6, c = idx & 63;          // r: n-row, c: k-col
    dst[(size_t)(n0 + r) * K + (k0 + c)] = f2bf(tile[c * 65 + r]);
  }
}

// ---------------- prep: X[e][0:512]=bf16(pred); pos[e][0:128] = 3-layer FCN via MFMA.
__global__ __launch_bounds__(256) void prep_kernel(
    const float* __restrict__ pred, const float* __restrict__ centroid,
    const float* __restrict__ pw1, const float* __restrict__ pb1,
    const float* __restrict__ pw2, const float* __restrict__ pb2,
    const float* __restrict__ pw3, const float* __restrict__ pb3,
    ushort_t* __restrict__ X, ushort_t* __restrict__ pos, int nm1)
{
  __shared__ ushort_t h1s[128 * 64];     // swizzled [128][64]
  __shared__ ushort_t h2s[128 * 64];     // swizzled [128][64]
  __shared__ ushort_t w2t[64 * 64];      // swizzled [n=64][k=64], w2t[n][k]=w2[k][n]
  __shared__ ushort_t w3t[128 * 64];     // swizzled [n=128][k=64]
  __shared__ float w1s[5 * 64];
  __shared__ float b1s[64], b2s[64], b3s[128];
  int t = threadIdx.x;
  for (int idx = t; idx < 64 * 64; idx += 256) {
    int k = idx >> 6, n = idx & 63;
    *(ushort_t*)((char*)w2t + swz(n, k * 2)) = f2bf(pw2[idx]);
  }
  for (int idx = t; idx < 64 * 128; idx += 256) {
    int k = idx >> 7, n = idx & 127;
    *(ushort_t*)((char*)w3t + swz(n, k * 2)) = f2bf(pw3[idx]);
  }
  for (int i = t; i < 5 * 64; i += 256) w1s[i] = pw1[i];
  if (t < 64) { b1s[t] = pb1[t]; b2s[t] = pb2[t]; }
  if (t < 128) b3s[t] = pb3[t];
  __syncthreads();   // race fix (r4): w1s/b1s read by all waves

  int wid = t >> 6, lane = t & 63;
  int ebase = blockIdx.x * 128 + wid * 32;
  for (int it = 0; it < 32; ++it) {
    int e = ebase + it;
    const float* pr = pred + (size_t)e * 512 + lane * 8;
    float4 pA = *(const float4*)pr;
    float4 pB = *(const float4*)(pr + 4);
    u16x8 o;
    o[0] = f2bf(pA.x); o[1] = f2bf(pA.y); o[2] = f2bf(pA.z); o[3] = f2bf(pA.w);
    o[4] = f2bf(pB.x); o[5] = f2bf(pB.y); o[6] = f2bf(pB.z); o[7] = f2bf(pB.w);
    *(u16x8*)(X + (size_t)e * 512 + lane * 8) = o;
    int i = e / nm1;
    int r = e - i * nm1;
    int j = r + (r >= i ? 1 : 0);
    float dx = centroid[i * 3 + 0] - centroid[j * 3 + 0];
    float dy = centroid[i * 3 + 1] - centroid[j * 3 + 1];
    float dist = sqrtf(dx * dx + dy * dy);
    float inv = 1.0f / dist;
    float h1 = w1s[0 * 64 + lane] * dx + w1s[1 * 64 + lane] * dy + w1s[2 * 64 + lane] * dist
             + w1s[3 * 64 + lane] * (dx * inv) + w1s[4 * 64 + lane] * (dy * inv) + b1s[lane];
    h1 = fmaxf(h1, 0.0f);
    int row = wid * 32 + it;
    *(ushort_t*)((char*)h1s + swz(row, lane * 2)) = f2bf(h1);
  }
  __syncthreads();

  int colg = lane & 15, rowg = (lane >> 4) << 2;
  int ko_lane = (lane >> 4) * 8;
  // ---- layer2: h2(32x64 per wave) = relu(h1 @ w2), K=64
  {
    f32x4 acc[2][4];
    f32x4 zero = {0.0f, 0.0f, 0.0f, 0.0f};
#pragma unroll
    for (int m_ = 0; m_ < 2; ++m_)
#pragma unroll
      for (int n_ = 0; n_ < 4; ++n_) acc[m_][n_] = zero;
#pragma unroll
    for (int kk = 0; kk < 2; ++kk) {
      int ko = kk * 32 + ko_lane;
      short8 a[2], b[4];
#pragma unroll
      for (int m_ = 0; m_ < 2; ++m_)
        a[m_] = *(const short8*)((const char*)h1s + swz(wid * 32 + m_ * 16 + colg, ko * 2));
#pragma unroll
      for (int n_ = 0; n_ < 4; ++n_)
        b[n_] = *(const short8*)((const char*)w2t + swz(n_ * 16 + colg, ko * 2));
#pragma unroll
      for (int m_ = 0; m_ < 2; ++m_)
#pragma unroll
        for (int n_ = 0; n_ < 4; ++n_)
          acc[m_][n_] = __builtin_amdgcn_mfma_f32_16x16x32_bf16(a[m_], b[n_], acc[m_][n_], 0, 0, 0);
    }
#pragma unroll
    for (int n_ = 0; n_ < 4; ++n_) {
      int col = n_ * 16 + colg;
      float bv = b2s[col];
#pragma unroll
      for (int m_ = 0; m_ < 2; ++m_) {
        int row = wid * 32 + m_ * 16 + rowg;
#pragma unroll
        for (int jj = 0; jj < 4; ++jj) {
          float v = fmaxf(acc[m_][n_][jj] + bv, 0.0f);
          *(ushort_t*)((char*)h2s + swz(row + jj, col * 2)) = f2bf(v);
        }
      }
    }
  }
  __syncthreads();
  // ---- layer3: pos(32x128 per wave) = h2 @ w3 (linear), K=64
  {
    f32x4 acc[2][8];
    f32x4 zero = {0.0f, 0.0f, 0.0f, 0.0f};
#pragma unroll
    for (int m_ = 0; m_ < 2; ++m_)
#pragma unroll
      for (int n_ = 0; n_ < 8; ++n_) acc[m_][n_] = zero;
#pragma unroll
    for (int kk = 0; kk < 2; ++kk) {
      int ko = kk * 32 + ko_lane;
      short8 a[2], b[8];
#pragma unroll
      for (int m_ = 0; m_ < 2; ++m_)
        a[m_] = *(const short8*)((const char*)h2s + swz(wid * 32 + m_ * 16 + colg, ko * 2));
#pragma unroll
      for (int n_ = 0; n_ < 8; ++n_)
        b[n_] = *(const short8*)((const char*)w3t + swz(n_ * 16 + colg, ko * 2));
#pragma unroll
      for (int m_ = 0; m_ < 2; ++m_)
#pragma unroll
        for (int n_ = 0; n_ < 8; ++n_)
          acc[m_][n_] = __builtin_amdgcn_mfma_f32_16x16x32_bf16(a[m_], b[n_], acc[m_][n_], 0, 0, 0);
    }
#pragma unroll
    for (int n_ = 0; n_ < 8; ++n_) {
      int col = n_ * 16 + colg;
      float bv = b3s[col];
#pragma unroll
      for (int m_ = 0; m_ < 2; ++m_) {
        int row = wid * 32 + m_ * 16 + rowg;
#pragma unroll
        for (int jj = 0; jj < 4; ++jj) {
          int e = blockIdx.x * 128 + row + jj;
          pos[(size_t)e * 128 + col] = f2bf(acc[m_][n_][jj] + bv);
        }
      }
    }
  }
}

// ---------------- GEMM C(M,512) = relu(A(M,K) @ W(K,512) + bias), f32 accum
// m97 structure: 128x128 tile, BK=64, 4 waves (2x2).
// A: up to 3 concatenated-K segments (kt<s0 -> A0, kt<s1 -> A1, else A2).
//   aF32=0: A is bf16, staged via global_load_lds width 16.
//   aF32=1: A is f32,  reg-staged with on-the-fly f32->bf16 convert (fallback only).
// Cout: outF32=1 -> float*, else bf16. Cdual (optional): extra bf16 store.
__global__ __launch_bounds__(256) void gemm_bias_relu(
    const void* __restrict__ A0, int lda0,
    const void* __restrict__ A1, int lda1,
    const void* __restrict__ A2, int lda2,
    int s0, int s1, int aF32,
    const ushort_t* __restrict__ Bt, const float* __restrict__ bias,
    void* __restrict__ Cout, int outF32, ushort_t* __restrict__ Cdual, int K)
{
  __shared__ ushort_t As[128 * 64];
  __shared__ ushort_t Bs[128 * 64];
  int bid = blockIdx.x;
  int cpx = gridDim.x >> 3;                    // grid % 8 == 0 (2040)
  int swzb = (bid & 7) * cpx + (bid >> 3);     // XCD-aware swizzle (bijective)
  int mt = swzb >> 2, nt = swzb & 3;
  int m0 = mt << 7, n0 = nt << 7;
  int t = threadIdx.x;
  int lane = t & 63, wid = t >> 6;
  int wm = wid >> 1, wn = wid & 1;
  f32x4 acc[4][4];
  f32x4 zero = {0.0f, 0.0f, 0.0f, 0.0f};
#pragma unroll
  for (int a_ = 0; a_ < 4; ++a_)
#pragma unroll
    for (int b_ = 0; b_ < 4; ++b_) acc[a_][b_] = zero;

  for (int kt = 0; kt < K; kt += 64) {
    const void* Ab; int ldaA; int kin;
    if (kt < s0)      { Ab = A0; ldaA = lda0; kin = kt; }
    else if (kt < s1) { Ab = A1; ldaA = lda1; kin = kt - s0; }
    else              { Ab = A2; ldaA = lda2; kin = kt - s1; }
    if (aF32) {
      const float* Af = (const float*)Ab;
      int rr = t >> 1, cc0 = (t & 1) << 5;
      const float* g = Af + (size_t)(m0 + rr) * ldaA + kin + cc0;
      ushort_t* ldst = As + rr * 64 + cc0;
#pragma unroll
      for (int i = 0; i < 4; ++i) {
        float4 v0 = *(const float4*)(g + i * 8);
        float4 v1 = *(const float4*)(g + i * 8 + 4);
        u16x8 o;
        o[0] = f2bf(v0.x); o[1] = f2bf(v0.y); o[2] = f2bf(v0.z); o[3] = f2bf(v0.w);
        o[4] = f2bf(v1.x); o[5] = f2bf(v1.y); o[6] = f2bf(v1.z); o[7] = f2bf(v1.w);
        *(u16x8*)(ldst + i * 8) = o;
      }
    } else {
      const ushort_t* Ah = (const ushort_t*)Ab;
#pragma unroll
      for (int i = 0; i < 4; ++i) {
        int ch = i * 256 + t;
        int rr = ch >> 3, cc = (ch & 7) << 3;
        const ushort_t* g = Ah + (size_t)(m0 + rr) * ldaA + kin + cc;
        __builtin_amdgcn_global_load_lds((const GLOBAL_AS void*)g,
                                         (LDS_AS void*)(As + ch * 8), 16, 0, 0);
      }
    }
#pragma unroll
    for (int i = 0; i < 4; ++i) {
      int ch = i * 256 + t;
      int rr = ch >> 3, cc = (ch & 7) << 3;
      const ushort_t* g = Bt + (size_t)(n0 + rr) * K + kt + cc;
      __builtin_amdgcn_global_load_lds((const GLOBAL_AS void*)g,
                                       (LDS_AS void*)(Bs + ch * 8), 16, 0, 0);
    }
    __syncthreads();
#pragma unroll
    for (int kk = 0; kk < 64; kk += 32) {
      int ko = kk + (lane >> 4) * 8;
      short8 a[4], b[4];
#pragma unroll
      for (int m_ = 0; m_ < 4; ++m_)
        a[m_] = *(const short8*)(As + (wm * 64 + m_ * 16 + (lane & 15)) * 64 + ko);
#pragma unroll
      for (int n_ = 0; n_ < 4; ++n_)
        b[n_] = *(const short8*)(Bs + (wn * 64 + n_ * 16 + (lane & 15)) * 64 + ko);
#pragma unroll
      for (int m_ = 0; m_ < 4; ++m_)
#pragma unroll
        for (int n_ = 0; n_ < 4; ++n_)
          acc[m_][n_] = __builtin_amdgcn_mfma_f32_16x16x32_bf16(a[m_], b[n_], acc[m_][n_], 0, 0, 0);
    }
    __syncthreads();
  }
  // epilogue: C/D layout col=lane&15, row=(lane>>4)*4+jj (m89-verified)
  int colg = lane & 15, rowg = (lane >> 4) << 2;
  float* C32 = (float*)Cout;
  ushort_t* C16 = (ushort_t*)Cout;
#pragma unroll
  for (int n_ = 0; n_ < 4; ++n_) {
    int col = n0 + wn * 64 + n_ * 16 + colg;
    float bv = bias[col];
#pragma unroll
    for (int m_ = 0; m_ < 4; ++m_) {
      int row = m0 + wm * 64 + m_ * 16 + rowg;
#pragma unroll
      for (int jj = 0; jj < 4; ++jj) {
        float v = fmaxf(acc[m_][n_][jj] + bv, 0.0f);
        if (outF32) C32[(size_t)(row + jj) * 512 + col] = v;
        else        C16[(size_t)(row + jj) * 512 + col] = f2bf(v);
        if (Cdual)  Cdual[(size_t)(row + jj) * 512 + col] = f2bf(v);
      }
    }
  }
}

extern "C" void kernel_launch(void* const* d_in, const int* in_sizes, int n_in,
                              void* d_out, int out_size, void* d_ws, size_t ws_size,
                              hipStream_t stream) {
  (void)n_in; (void)out_size;
  const float* pred = (const float*)d_in[1];
  const float* centroid = (const float*)d_in[4];
  const float* W[8] = { (const float*)d_in[5],  (const float*)d_in[7],  (const float*)d_in[9],
                        (const float*)d_in[11], (const float*)d_in[13], (const float*)d_in[15],
                        (const float*)d_in[17], (const float*)d_in[19] };
  const float* Bv[8] = { (const float*)d_in[6],  (const float*)d_in[8],  (const float*)d_in[10],
                         (const float*)d_in[12], (const float*)d_in[14], (const float*)d_in[16],
                         (const float*)d_in[18], (const float*)d_in[20] };
  int Kd[8] = {512, 512, 640, 512, 512, 512, 1536, 512};
  const float* pos_w1 = (const float*)d_in[21]; const float* pos_b1 = (const float*)d_in[22];
  const float* pos_w2 = (const float*)d_in[23]; const float* pos_b2 = (const float*)d_in[24];
  const float* pos_w3 = (const float*)d_in[25]; const float* pos_b3 = (const float*)d_in[26];

  int E = in_sizes[1] / 512;       // 65280
  int n = in_sizes[4] / 3;         // 256

  char* ws = (char*)d_ws;
  size_t off = 0;
  auto alloc = [&](size_t bytes) -> void* {
    void* p = ws + off;
    off = (off + bytes + 255) & ~(size_t)255;
    return p;
  };
  size_t SB = (size_t)E * 512 * 2;           // one bf16 activation slab (66.8 MB)
  ushort_t* Wt[8];
  for (int i = 0; i < 8; ++i) Wt[i] = (ushort_t*)alloc((size_t)Kd[i] * 512 * 2);
  ushort_t* X = (ushort_t*)alloc(SB);        // bf16 pred; reused as comp16 after comp-L1
  size_t base_need = off;
  ushort_t* Hb_ws    = (ushort_t*)alloc(SB); // branch hidden (fast path); reused as link hidden
  ushort_t* sup16_ws = (ushort_t*)alloc(SB);
  bool fast = (off <= ws_size);              // need ~206 MB

  // ---- d_out: FLOAT32, 4 slots of E*512.
  float* outF = (float*)d_out;
  size_t S = (size_t)E * 512;
  float* out_link = outF;
  float* out_sup  = outF + S;
  float* out_prox = outF + 2 * S;
  float* out_comp = outF + 3 * S;
  ushort_t* pos = (ushort_t*)d_out;          // slot0 bytes 0..16.7MB, dead after prox-L1

  TransArgs ta;
  int nblk = 0;
  for (int i = 0; i < 8; ++i) {
    ta.src[i] = W[i]; ta.dst[i] = Wt[i]; ta.K[i] = Kd[i];
    ta.blk0[i] = nblk;
    nblk += (Kd[i] >> 6) * 8;
  }
  ta.blk0[8] = nblk;
  hipLaunchKernelGGL(transpose_weights, dim3(nblk), dim3(256), 0, stream, ta);
  hipLaunchKernelGGL(prep_kernel, dim3(E / 128), dim3(256), 0, stream,
                     pred, centroid, pos_w1, pos_b1, pos_w2, pos_b2, pos_w3, pos_b3,
                     X, pos, n - 1);

  dim3 g(E / 128 * 4), blk(256);
  const void* Z = nullptr;
  ushort_t* NO16 = nullptr;

  if (fast) {
    // Fast path: all link-L1 inputs as bf16 via dual-store; everything async-staged.
    // Regions: Hb=ws, sup16=ws, comp16=X-region (X dead after comp-L1),
    //          prox16=slot0 bytes 0..66.9MB (pos dead), Hl=Hb-region (dead after comp-L2).
    ushort_t* prox16 = (ushort_t*)d_out;
    ushort_t* comp16 = X;
    ushort_t* Hl = Hb_ws;
    (void)base_need;
    // proximity (first: consumes pos before prox16 overwrites slot0 head)
    hipLaunchKernelGGL(gemm_bias_relu, g, blk, 0, stream,
                       (const void*)X, 512, (const void*)pos, 128, Z, 0, 512, 640, 0,
                       Wt[2], Bv[2], (void*)Hb_ws, 0, NO16, 640);
    hipLaunchKernelGGL(gemm_bias_relu, g, blk, 0, stream,
                       (const void*)Hb_ws, 512, Z, 0, Z, 0, 512, 512, 0,
                       Wt[3], Bv[3], (void*)out_prox, 1, prox16, 512);
    // support
    hipLaunchKernelGGL(gemm_bias_relu, g, blk, 0, stream,
                       (const void*)X, 512, Z, 0, Z, 0, 512, 512, 0,
                       Wt[0], Bv[0], (void*)Hb_ws, 0, NO16, 512);
    hipLaunchKernelGGL(gemm_bias_relu, g, blk, 0, stream,
                       (const void*)Hb_ws, 512, Z, 0, Z, 0, 512, 512, 0,
                       Wt[1], Bv[1], (void*)out_sup, 1, sup16_ws, 512);
    // comp (last use of X as input; comp16 then reuses X region)
    hipLaunchKernelGGL(gemm_bias_relu, g, blk, 0, stream,
                       (const void*)X, 512, Z, 0, Z, 0, 512, 512, 0,
                       Wt[4], Bv[4], (void*)Hb_ws, 0, NO16, 512);
    hipLaunchKernelGGL(gemm_bias_relu, g, blk, 0, stream,
                       (const void*)Hb_ws, 512, Z, 0, Z, 0, 512, 512, 0,
                       Wt[5], Bv[5], (void*)out_comp, 1, comp16, 512);
    // link-L1: bf16 segmented A = [sup16 | prox16 | comp16] -> Hl (= Hb region, dead)
    hipLaunchKernelGGL(gemm_bias_relu, g, blk, 0, stream,
                       (const void*)sup16_ws, 512, (const void*)prox16, 512,
                       (const void*)comp16, 512, 512, 1024, 0,
                       Wt[6], Bv[6], (void*)Hl, 0, NO16, 1536);
    // link-L2: Hl (ws) -> slot0 f32 (prox16 in slot0 is dead)
    hipLaunchKernelGGL(gemm_bias_relu, g, blk, 0, stream,
                       (const void*)Hl, 512, Z, 0, Z, 0, 512, 512, 0,
                       Wt[7], Bv[7], (void*)out_link, 1, NO16, 512);
  } else {
    // Fallback (round-5 passing plan): Hb in slot0+32MB, aF32 link-L1, Hl=X region.
    ushort_t* Hb = (ushort_t*)((char*)d_out + (size_t)32 * 1024 * 1024);
    ushort_t* Hl = X;
    hipLaunchKernelGGL(gemm_bias_relu, g, blk, 0, stream,
                       (const void*)X, 512, (const void*)pos, 128, Z, 0, 512, 640, 0,
                       Wt[2], Bv[2], (void*)Hb, 0, NO16, 640);
    hipLaunchKernelGGL(gemm_bias_relu, g, blk, 0, stream,
                       (const void*)Hb, 512, Z, 0, Z, 0, 512, 512, 0,
                       Wt[3], Bv[3], (void*)out_prox, 1, NO16, 512);
    hipLaunchKernelGGL(gemm_bias_relu, g, blk, 0, stream,
                       (const void*)X, 512, Z, 0, Z, 0, 512, 512, 0,
                       Wt[0], Bv[0], (void*)Hb, 0, NO16, 512);
    hipLaunchKernelGGL(gemm_bias_relu, g, blk, 0, stream,
                       (const void*)Hb, 512, Z, 0, Z, 0, 512, 512, 0,
                       Wt[1], Bv[1], (void*)out_sup, 1, NO16, 512);
    hipLaunchKernelGGL(gemm_bias_relu, g, blk, 0, stream,
                       (const void*)X, 512, Z, 0, Z, 0, 512, 512, 0,
                       Wt[4], Bv[4], (void*)Hb, 0, NO16, 512);
    hipLaunchKernelGGL(gemm_bias_relu, g, blk, 0, stream,
                       (const void*)Hb, 512, Z, 0, Z, 0, 512, 512, 0,
                       Wt[5], Bv[5], (void*)out_comp, 1, NO16, 512);
    hipLaunchKernelGGL(gemm_bias_relu, g, blk, 0, stream,
                       (const void*)out_sup, 512, (const void*)out_prox, 512,
                       (const void*)out_comp, 512, 512, 1024, 1,
                       Wt[6], Bv[6], (void*)Hl, 0, NO16, 1536);
    hipLaunchKernelGGL(gemm_bias_relu, g, blk, 0, stream,
                       (const void*)Hl, 512, Z, 0, Z, 0, 512, 512, 0,
                       Wt[7], Bv[7], (void*)out_link, 1, NO16, 512);
  }
}